// Round 1
// baseline (4386.024 us; speedup 1.0000x reference)
//
#include <hip/hip_runtime.h>
#include <hip/hip_bf16.h>

// Problem dims
#define B_SZ 4096
#define T_SZ 64
#define F_SZ 89
#define H_SZ 1024
#define O_SZ 89

// GEMM tiling
#define KX   128               // padded x-part of K (89 -> 128)
#define KTOT (KX + H_SZ)       // 1152
#define BK   64
#define NKB  (KTOT / BK)       // 18
#define BM   128
#define BNH  32                // h-columns per block; packed N = 4 gates * 32 = 128

typedef __attribute__((ext_vector_type(8))) short bf16x8;
typedef __attribute__((ext_vector_type(4))) float f32x4;

__device__ __forceinline__ void gload_lds16(const void* g, void* l) {
  __builtin_amdgcn_global_load_lds((const __attribute__((address_space(1))) void*)g,
                                   (__attribute__((address_space(3))) void*)l,
                                   16, 0, 0);
}

__device__ __forceinline__ float sigmoidf_(float x) {
  return 1.0f / (1.0f + __expf(-x));
}

// Build WT [4096 n][1152 k] bf16 = transpose of [Wk(89,pad128); Wr(1024)] -> so
// B-tiles are k-contiguous per output column (ds_read_b128-friendly, linear LDS).
__global__ __launch_bounds__(256) void pack_w(const float* __restrict__ Wk,
                                              const float* __restrict__ Wr,
                                              __hip_bfloat16* __restrict__ WT) {
  __shared__ float tile[64][65];
  const int n0 = blockIdx.x * 64;
  const int k0 = blockIdx.y * 64;
  const int c  = threadIdx.x & 63;
  const int rq = threadIdx.x >> 6;  // 0..3
  for (int j = 0; j < 16; ++j) {
    int kk = rq * 16 + j;
    int k = k0 + kk;
    float v;
    if (k < KX) v = (k < F_SZ) ? Wk[(size_t)k * 4096 + n0 + c] : 0.0f;
    else        v = Wr[(size_t)(k - KX) * 4096 + n0 + c];
    tile[kk][c] = v;
  }
  __syncthreads();
  for (int j = 0; j < 16; ++j) {
    int nn = rq * 16 + j;
    WT[(size_t)(n0 + nn) * KTOT + k0 + c] = __float2bfloat16(tile[c][nn]);
  }
}

// xp [T][B][128] bf16, zero-padded cols 89..127 (time-major so per-step slice is contiguous)
__global__ __launch_bounds__(256) void pack_x(const float* __restrict__ x,
                                              __hip_bfloat16* __restrict__ xp) {
  const int m = blockIdx.y;
  const int t = blockIdx.x * 2 + (threadIdx.x >> 7);
  const int f = threadIdx.x & 127;
  float v = (f < F_SZ) ? x[((size_t)m * T_SZ + t) * F_SZ + f] : 0.0f;
  xp[((size_t)t * B_SZ + m) * KX + f] = __float2bfloat16(v);
}

// One LSTM step: z = [x_t | h_in] @ [Wk;Wr]^ + b, gates, c/h update.
// Block computes BM=128 rows x (4 gates x 32 h-cols). 4 waves, each wave owns
// 32 rows x all 128 packed cols: acc[2][8] of 16x16 tiles, mfma_f32_16x16x32_bf16.
__global__ __launch_bounds__(256, 2)
void lstm_step(const __hip_bfloat16* __restrict__ xp_t,   // [4096][128]
               const __hip_bfloat16* __restrict__ h_in,   // [4096][1024]
               __hip_bfloat16* __restrict__ h_out,        // [4096][1024]
               float* __restrict__ cbuf,                  // [4096][1024]
               const __hip_bfloat16* __restrict__ WT,     // [4096][1152]
               const float* __restrict__ bias,            // [4096]
               float* __restrict__ h_last)                // null or [4096][1024] f32
{
  __shared__ __attribute__((aligned(16))) short As[BM * BK];   // [128 m][64 k]
  __shared__ __attribute__((aligned(16))) short Bs[128 * BK];  // [128 packed-n][64 k]

  const int tid  = threadIdx.x;
  const int lane = tid & 63;
  const int w    = tid >> 6;            // wave 0..3
  const int m0   = blockIdx.x * BM;
  const int n0h  = blockIdx.y * BNH;

  const int srow = lane >> 3;           // 0..7  (staging row within 8-row group)
  const int scol = (lane & 7) << 3;     // 0..56 (staging col, 8 bf16 = 16B)
  const int lr   = lane & 15;
  const int lq   = lane >> 4;           // 0..3

  f32x4 acc[2][8];
#pragma unroll
  for (int mi = 0; mi < 2; ++mi)
#pragma unroll
    for (int ni = 0; ni < 8; ++ni) acc[mi][ni] = (f32x4){0.f, 0.f, 0.f, 0.f};

  for (int kb = 0; kb < NKB; ++kb) {
    // ---- stage A tile [128][64] ----
    const __hip_bfloat16* asrc;
    int lda;
    if (kb < 2) { asrc = xp_t + (size_t)m0 * KX + kb * BK;          lda = KX; }
    else        { asrc = h_in + (size_t)m0 * H_SZ + (kb * BK - KX); lda = H_SZ; }
#pragma unroll
    for (int i = 0; i < 4; ++i) {
      int r = w * 32 + i * 8 + srow;
      gload_lds16(asrc + (size_t)r * lda + scol, &As[(w * 32 + i * 8) * BK]);
    }
    // ---- stage B tile [128 packed][64] from WT rows (strip = wave id) ----
#pragma unroll
    for (int i = 0; i < 4; ++i) {
      int n = n0h + w * H_SZ + i * 8 + srow;  // packed p = w*32+i*8+srow, gate strip = w
      gload_lds16(WT + (size_t)n * KTOT + kb * BK + scol, &Bs[(w * 32 + i * 8) * BK]);
    }
    __syncthreads();  // compiler drains vmcnt(0) before barrier

    // ---- MFMA ----
#pragma unroll
    for (int ks = 0; ks < 2; ++ks) {
      const int koff = ks * 32 + lq * 8;
      bf16x8 a[2], bf[8];
#pragma unroll
      for (int mi = 0; mi < 2; ++mi)
        a[mi] = *(const bf16x8*)&As[(w * 32 + mi * 16 + lr) * BK + koff];
#pragma unroll
      for (int ni = 0; ni < 8; ++ni)
        bf[ni] = *(const bf16x8*)&Bs[(ni * 16 + lr) * BK + koff];
#pragma unroll
      for (int mi = 0; mi < 2; ++mi)
#pragma unroll
        for (int ni = 0; ni < 8; ++ni)
          acc[mi][ni] = __builtin_amdgcn_mfma_f32_16x16x32_bf16(a[mi], bf[ni], acc[mi][ni], 0, 0, 0);
    }
    __syncthreads();
  }

  // ---- epilogue: gates + cell update ----
  // rows: r = m0 + w*32 + mi*16 + lq*4 + v ; cols: hc = n0h + hf*16 + lr
  // gate strip s = ni/2 -> i:acc[.][0+hf] f:acc[.][2+hf] g:acc[.][4+hf] o:acc[.][6+hf]
#pragma unroll
  for (int hf = 0; hf < 2; ++hf) {
    const int hc = n0h + hf * 16 + lr;
    const float bi = bias[hc];
    const float bff = bias[H_SZ + hc];
    const float bg = bias[2 * H_SZ + hc];
    const float bo = bias[3 * H_SZ + hc];
#pragma unroll
    for (int mi = 0; mi < 2; ++mi) {
      f32x4 zi = acc[mi][0 + hf], zf = acc[mi][2 + hf];
      f32x4 zg = acc[mi][4 + hf], zo = acc[mi][6 + hf];
#pragma unroll
      for (int v = 0; v < 4; ++v) {
        int r = m0 + w * 32 + mi * 16 + lq * 4 + v;
        size_t idx = (size_t)r * H_SZ + hc;
        float iv = sigmoidf_(zi[v] + bi);
        float fv = sigmoidf_(zf[v] + bff);
        float gv = fmaxf(zg[v] + bg, 0.0f);
        float ov = sigmoidf_(zo[v] + bo);
        float cn = fv * cbuf[idx] + iv * gv;
        cbuf[idx] = cn;
        float hv = ov * fmaxf(cn, 0.0f);
        h_out[idx] = __float2bfloat16(hv);
        if (h_last) h_last[idx] = hv;
      }
    }
  }
}

// out[4096][89] = h_last @ Wd + bd  (fp32)
__global__ __launch_bounds__(256) void dense_k(const float* __restrict__ hl,
                                               const float* __restrict__ Wd,
                                               const float* __restrict__ bd,
                                               float* __restrict__ out) {
  __shared__ float hrow[8][1024];
  const int r0 = blockIdx.x * 8;
  for (int i = threadIdx.x; i < 8 * 1024; i += 256)
    hrow[i >> 10][i & 1023] = hl[(size_t)r0 * 1024 + i];
  __syncthreads();
  for (int idx = threadIdx.x; idx < 8 * O_SZ; idx += 256) {
    int rr = idx / O_SZ, o = idx - rr * O_SZ;
    float s = bd[o];
    const float* hp = hrow[rr];
#pragma unroll 8
    for (int k = 0; k < 1024; ++k) s += hp[k] * Wd[(size_t)k * O_SZ + o];
    out[(size_t)(r0 + rr) * O_SZ + o] = s;
  }
}

extern "C" void kernel_launch(void* const* d_in, const int* in_sizes, int n_in,
                              void* d_out, int out_size, void* d_ws, size_t ws_size,
                              hipStream_t stream) {
  const float* x  = (const float*)d_in[0];
  const float* Wk = (const float*)d_in[1];
  const float* Wr = (const float*)d_in[2];
  const float* b  = (const float*)d_in[3];
  const float* Wd = (const float*)d_in[4];
  const float* bd = (const float*)d_in[5];
  float* out = (float*)d_out;

  char* ws = (char*)d_ws;
  size_t off = 0;
  auto carve = [&](size_t bytes) -> char* {
    char* p = ws + off;
    off += (bytes + 255) & ~(size_t)255;
    return p;
  };
  __hip_bfloat16* WT   = (__hip_bfloat16*)carve((size_t)4096 * KTOT * 2);      //  9.4 MB
  __hip_bfloat16* xp   = (__hip_bfloat16*)carve((size_t)T_SZ * B_SZ * KX * 2); // 67.1 MB
  __hip_bfloat16* h0   = (__hip_bfloat16*)carve((size_t)B_SZ * H_SZ * 2);      //  8.4 MB
  __hip_bfloat16* h1   = (__hip_bfloat16*)carve((size_t)B_SZ * H_SZ * 2);      //  8.4 MB
  float*          cbuf = (float*)carve((size_t)B_SZ * H_SZ * 4);               // 16.8 MB
  float*          hlast= (float*)carve((size_t)B_SZ * H_SZ * 4);               // 16.8 MB

  // zero initial state (ws is re-poisoned before every call)
  hipMemsetAsync(h0, 0, (size_t)B_SZ * H_SZ * 2, stream);
  hipMemsetAsync(cbuf, 0, (size_t)B_SZ * H_SZ * 4, stream);

  pack_w<<<dim3(64, 18), 256, 0, stream>>>(Wk, Wr, WT);
  pack_x<<<dim3(32, B_SZ), 256, 0, stream>>>(x, xp);

  __hip_bfloat16* hbuf[2] = {h0, h1};
  for (int t = 0; t < T_SZ; ++t) {
    const __hip_bfloat16* xpt = xp + (size_t)t * B_SZ * KX;
    float* hl = (t == T_SZ - 1) ? hlast : nullptr;
    lstm_step<<<dim3(32, 32), 256, 0, stream>>>(xpt, hbuf[t & 1], hbuf[(t + 1) & 1],
                                                cbuf, WT, b, hl);
  }

  dense_k<<<dim3(B_SZ / 8), 256, 0, stream>>>(hlast, Wd, bd, out);
}

// Round 2
// 3099.384 us; speedup vs baseline: 1.4151x; 1.4151x over previous
//
#include <hip/hip_runtime.h>
#include <hip/hip_bf16.h>

#define B_SZ 4096
#define T_SZ 64
#define F_SZ 89
#define H_SZ 1024
#define O_SZ 89
#define KX   128
#define KTOT (KX + H_SZ)   // 1152
#define BK   64
#define NKB  (KTOT / BK)   // 18

typedef __attribute__((ext_vector_type(8))) short bf16x8;
typedef __attribute__((ext_vector_type(4))) float f32x4;

__device__ __forceinline__ void gload_lds16(const void* g, void* l) {
  __builtin_amdgcn_global_load_lds((const __attribute__((address_space(1))) void*)g,
                                   (__attribute__((address_space(3))) void*)l,
                                   16, 0, 0);
}
__device__ __forceinline__ float sigmoidf_(float x) {
  return 1.0f / (1.0f + __expf(-x));
}

// WT2 packed: n' = (h>>4)*64 + g*16 + (h&15), bf16, [4096][1152] k-contiguous rows.
__global__ __launch_bounds__(256) void pack_w(const float* __restrict__ Wk,
                                              const float* __restrict__ Wr,
                                              __hip_bfloat16* __restrict__ WT2) {
  __shared__ float tile[64][65];
  const int n0 = blockIdx.x * 64;   // orig gate-major column block
  const int k0 = blockIdx.y * 64;
  const int c  = threadIdx.x & 63;
  const int rq = threadIdx.x >> 6;
  for (int j = 0; j < 16; ++j) {
    int kk = rq * 16 + j;
    int k = k0 + kk;
    float v;
    if (k < KX) v = (k < F_SZ) ? Wk[(size_t)k * 4096 + n0 + c] : 0.0f;
    else        v = Wr[(size_t)(k - KX) * 4096 + n0 + c];
    tile[kk][c] = v;
  }
  __syncthreads();
  for (int j = 0; j < 16; ++j) {
    int R = n0 + rq * 16 + j;          // orig row: g*1024 + h
    int g = R >> 10, h = R & 1023;
    int np = ((h >> 4) << 6) + (g << 4) + (h & 15);
    WT2[(size_t)np * KTOT + k0 + c] = __float2bfloat16(tile[c][rq * 16 + j]);
  }
}

// xp [T][B][128] bf16, zero-padded cols 89..127
__global__ __launch_bounds__(256) void pack_x(const float* __restrict__ x,
                                              __hip_bfloat16* __restrict__ xp) {
  const int m = blockIdx.y;
  const int t = blockIdx.x * 2 + (threadIdx.x >> 7);
  const int f = threadIdx.x & 127;
  float v = (f < F_SZ) ? x[((size_t)m * T_SZ + t) * F_SZ + f] : 0.0f;
  xp[((size_t)t * B_SZ + m) * KX + f] = __float2bfloat16(v);
}

// WdT2[2][96][1024] bf16: pass0 = bf16(Wd^T), pass1 = bf16(Wd^T - pass0)
__global__ __launch_bounds__(256) void pack_wd(const float* __restrict__ Wd,
                                               __hip_bfloat16* __restrict__ WdT2) {
  int o = blockIdx.x;  // 0..95
  for (int k = threadIdx.x; k < 1024; k += 256) {
    float v = (o < O_SZ) ? Wd[(size_t)k * O_SZ + o] : 0.0f;
    __hip_bfloat16 w1 = __float2bfloat16(v);
    WdT2[(size_t)o * 1024 + k] = w1;
    WdT2[96 * 1024 + (size_t)o * 1024 + k] = __float2bfloat16(v - __bfloat162float(w1));
  }
}

// ---------------- LSTM step: 256x256 tile, BK=64, 8 waves, 4-phase/K-tile ----------------
__global__ __launch_bounds__(512, 2)
void lstm_step(const __hip_bfloat16* __restrict__ xp_t,   // [4096][128]
               const __hip_bfloat16* __restrict__ h_in,   // [4096][1024]
               __hip_bfloat16* __restrict__ h_out,
               float* __restrict__ cbuf,
               const __hip_bfloat16* __restrict__ WT2,    // [4096][1152] packed
               const float* __restrict__ bias,
               __hip_bfloat16* __restrict__ h2_out)       // null or bf16 residual of h
{
  // A bufs @ 0 / 32768 ; B bufs @ 65536 / 98304 (each 256 rows x 128B)
  __shared__ __attribute__((aligned(1024))) char smem[131072];

  const int tid  = threadIdx.x;
  const int lane = tid & 63;
  const int w    = tid >> 6;
  const int wm   = w >> 2;     // 0..1  (M half)
  const int wn   = w & 3;      // 0..3  (64-col strip)

  // XCD-aware swizzle (nwg=256, 8 XCDs)
  const int bid = blockIdx.x;
  const int wg  = (bid & 7) * 32 + (bid >> 3);
  const int bx  = wg >> 4;     // M tile (XCD-local A panels)
  const int by  = wg & 15;     // N tile
  const int m0  = bx * 256;

  // staging coords (4 ops/thread per 32KB tile), st_16x32 swizzle on SOURCE col
  int srow[4], scol[4];
#pragma unroll
  for (int j = 0; j < 4; ++j) {
    int row = (w * 4 + j) * 8 + (lane >> 3);         // 0..255
    int sb  = (row >> 2) & 1;
    srow[j] = row;
    scol[j] = ((lane & 7) * 16) ^ (sb << 5);
  }
  const int lr  = lane & 15, lq = lane >> 4;
  const int xb5 = ((lr >> 2) & 1) << 5;              // read-side swizzle bit

  const char* bsrc0 = (const char*)(WT2 + (size_t)by * 256 * KTOT);

  f32x4 acc[8][4];
#pragma unroll
  for (int mi = 0; mi < 8; ++mi)
#pragma unroll
    for (int ni = 0; ni < 4; ++ni) acc[mi][ni] = (f32x4){0.f, 0.f, 0.f, 0.f};

  auto stageA = [&](int kt, int buf) {
    const char* base; int ldab;
    if (kt < 2) { base = (const char*)(xp_t + (size_t)m0 * KX + kt * BK);          ldab = KX * 2; }
    else        { base = (const char*)(h_in + (size_t)m0 * H_SZ + (kt * BK - KX)); ldab = H_SZ * 2; }
#pragma unroll
    for (int j = 0; j < 4; ++j)
      gload_lds16(base + (size_t)srow[j] * ldab + scol[j],
                  smem + buf * 32768 + (w * 4 + j) * 1024);
  };
  auto stageB = [&](int kt, int buf) {
#pragma unroll
    for (int j = 0; j < 4; ++j)
      gload_lds16(bsrc0 + (size_t)srow[j] * (KTOT * 2) + kt * (BK * 2) + scol[j],
                  smem + 65536 + buf * 32768 + (w * 4 + j) * 1024);
  };

  // prologue: stage tile 0 -> buf0, full drain once
  stageA(0, 0);
  stageB(0, 0);
  asm volatile("s_waitcnt vmcnt(0)" ::: "memory");
  __builtin_amdgcn_s_barrier();

  for (int kt = 0; kt < NKB; ++kt) {
    const int buf = kt & 1;
    const char* Ab = smem + buf * 32768 + wm * 16384;          // wave's 128 rows
    const char* Bb = smem + 65536 + buf * 32768 + wn * 64 * 128; // wave's 64 cols
    const bool havenext = (kt + 1 < NKB);
    bf16x8 Bf[4][2];

#pragma unroll
    for (int q = 0; q < 4; ++q) {
      // ---- ds-read frags for this phase ----
      if (q == 0) {
#pragma unroll
        for (int ni = 0; ni < 4; ++ni)
#pragma unroll
          for (int ks = 0; ks < 2; ++ks)
            Bf[ni][ks] = *(const bf16x8*)(Bb + (ni * 16 + lr) * 128 + ((ks * 64 + lq * 16) ^ xb5));
      }
      bf16x8 Af[2][2];
#pragma unroll
      for (int i = 0; i < 2; ++i)
#pragma unroll
        for (int ks = 0; ks < 2; ++ks)
          Af[i][ks] = *(const bf16x8*)(Ab + ((q * 2 + i) * 16 + lr) * 128 + ((ks * 64 + lq * 16) ^ xb5));

      // ---- issue next-tile staging early (targets the OTHER buffer: race-free) ----
      if (q == 0 && havenext) stageA(kt + 1, buf ^ 1);
      if (q == 1 && havenext) stageB(kt + 1, buf ^ 1);

      __builtin_amdgcn_s_barrier();
      asm volatile("s_waitcnt lgkmcnt(0)" ::: "memory");
      __builtin_amdgcn_sched_barrier(0);

      __builtin_amdgcn_s_setprio(1);
#pragma unroll
      for (int i = 0; i < 2; ++i)
#pragma unroll
        for (int ni = 0; ni < 4; ++ni)
#pragma unroll
          for (int ks = 0; ks < 2; ++ks)
            acc[q * 2 + i][ni] =
                __builtin_amdgcn_mfma_f32_16x16x32_bf16(Af[i][ks], Bf[ni][ks], acc[q * 2 + i][ni], 0, 0, 0);
      __builtin_amdgcn_s_setprio(0);

      if (q == 3) {
        // tile boundary: wait own stage loads (issued 2-3 phases ago), then join
        if (havenext) asm volatile("s_waitcnt vmcnt(0)" ::: "memory");
        __builtin_amdgcn_s_barrier();
      } else {
        __builtin_amdgcn_s_barrier();
      }
    }
  }

  // ---- epilogue: all 4 gates are wave-local (ni == gate) ----
  const int hcol = by * 64 + wn * 16 + lr;
  const float b0 = bias[hcol];
  const float b1 = bias[H_SZ + hcol];
  const float b2 = bias[2 * H_SZ + hcol];
  const float b3 = bias[3 * H_SZ + hcol];
#pragma unroll
  for (int mi = 0; mi < 8; ++mi) {
#pragma unroll
    for (int v = 0; v < 4; ++v) {
      int r = m0 + wm * 128 + mi * 16 + lq * 4 + v;
      size_t idx = (size_t)r * H_SZ + hcol;
      float iv = sigmoidf_(acc[mi][0][v] + b0);
      float fv = sigmoidf_(acc[mi][1][v] + b1);
      float gv = fmaxf(acc[mi][2][v] + b2, 0.0f);
      float ov = sigmoidf_(acc[mi][3][v] + b3);
      float cn = fv * cbuf[idx] + iv * gv;
      cbuf[idx] = cn;
      float hv = ov * fmaxf(cn, 0.0f);
      __hip_bfloat16 h1 = __float2bfloat16(hv);
      h_out[idx] = h1;
      if (h2_out) h2_out[idx] = __float2bfloat16(hv - __bfloat162float(h1));
    }
  }
}

// ---------------- dense: out = h @ Wd + bd via 3-pass bf16 MFMA (fp32-accurate) ----------------
__global__ __launch_bounds__(256)
void dense_k(const __hip_bfloat16* __restrict__ h1,
             const __hip_bfloat16* __restrict__ h2,
             const __hip_bfloat16* __restrict__ WdT2,  // [2][96][1024]
             const float* __restrict__ bd,
             float* __restrict__ out) {
  __shared__ __attribute__((aligned(1024))) char smem[16384 + 12288]; // A[128][64] + B[96][64]
  const int tid = threadIdx.x, lane = tid & 63, w = tid >> 6;
  const int m0 = blockIdx.x * 128;

  int srow[4], scol[4];
#pragma unroll
  for (int j = 0; j < 4; ++j) {
    int row = j * 32 + (tid >> 3);
    int sb  = (row >> 2) & 1;
    srow[j] = row;
    scol[j] = ((lane & 7) * 16) ^ (sb << 5);
  }
  const int lr = lane & 15, lq = lane >> 4;
  const int xb5 = ((lr >> 2) & 1) << 5;

  f32x4 acc[2][6];
#pragma unroll
  for (int mi = 0; mi < 2; ++mi)
#pragma unroll
    for (int ni = 0; ni < 6; ++ni) acc[mi][ni] = (f32x4){0.f, 0.f, 0.f, 0.f};

  for (int p = 0; p < 3; ++p) {
    const __hip_bfloat16* Asrc = (p < 2) ? h1 : h2;
    const __hip_bfloat16* Bsrc = WdT2 + (p == 1 ? 96 * 1024 : 0);
    for (int kb = 0; kb < 16; ++kb) {
      __syncthreads();  // previous reads done before overwrite
#pragma unroll
      for (int j = 0; j < 4; ++j)
        gload_lds16((const char*)(Asrc + (size_t)(m0 + srow[j]) * 1024 + kb * BK) + scol[j],
                    smem + j * 4096 + w * 1024);
#pragma unroll
      for (int j = 0; j < 3; ++j)
        gload_lds16((const char*)(Bsrc + (size_t)srow[j] * 1024 + kb * BK) + scol[j],
                    smem + 16384 + j * 4096 + w * 1024);
      __syncthreads();  // hipcc drains vmcnt(0) before barrier -> data resident

      bf16x8 Af[2][2], Bf[6][2];
#pragma unroll
      for (int i = 0; i < 2; ++i)
#pragma unroll
        for (int ks = 0; ks < 2; ++ks)
          Af[i][ks] = *(const bf16x8*)(smem + (w * 32 + i * 16 + lr) * 128 + ((ks * 64 + lq * 16) ^ xb5));
#pragma unroll
      for (int ni = 0; ni < 6; ++ni)
#pragma unroll
        for (int ks = 0; ks < 2; ++ks)
          Bf[ni][ks] = *(const bf16x8*)(smem + 16384 + (ni * 16 + lr) * 128 + ((ks * 64 + lq * 16) ^ xb5));
#pragma unroll
      for (int i = 0; i < 2; ++i)
#pragma unroll
        for (int ni = 0; ni < 6; ++ni)
#pragma unroll
          for (int ks = 0; ks < 2; ++ks)
            acc[i][ni] = __builtin_amdgcn_mfma_f32_16x16x32_bf16(Af[i][ks], Bf[ni][ks], acc[i][ni], 0, 0, 0);
    }
  }

#pragma unroll
  for (int i = 0; i < 2; ++i)
#pragma unroll
    for (int ni = 0; ni < 6; ++ni) {
      int o = ni * 16 + lr;
      if (o < O_SZ) {
        float bv = bd[o];
#pragma unroll
        for (int v = 0; v < 4; ++v) {
          int r = m0 + w * 32 + i * 16 + lq * 4 + v;
          out[(size_t)r * O_SZ + o] = acc[i][ni][v] + bv;
        }
      }
    }
}

extern "C" void kernel_launch(void* const* d_in, const int* in_sizes, int n_in,
                              void* d_out, int out_size, void* d_ws, size_t ws_size,
                              hipStream_t stream) {
  const float* x  = (const float*)d_in[0];
  const float* Wk = (const float*)d_in[1];
  const float* Wr = (const float*)d_in[2];
  const float* b  = (const float*)d_in[3];
  const float* Wd = (const float*)d_in[4];
  const float* bd = (const float*)d_in[5];
  float* out = (float*)d_out;

  char* ws = (char*)d_ws;
  size_t off = 0;
  auto carve = [&](size_t bytes) -> char* {
    char* p = ws + off;
    off += (bytes + 255) & ~(size_t)255;
    return p;
  };
  __hip_bfloat16* WT2  = (__hip_bfloat16*)carve((size_t)4096 * KTOT * 2);
  __hip_bfloat16* xp   = (__hip_bfloat16*)carve((size_t)T_SZ * B_SZ * KX * 2);
  __hip_bfloat16* h0   = (__hip_bfloat16*)carve((size_t)B_SZ * H_SZ * 2);
  __hip_bfloat16* h1b  = (__hip_bfloat16*)carve((size_t)B_SZ * H_SZ * 2);
  float*          cbuf = (float*)carve((size_t)B_SZ * H_SZ * 4);
  __hip_bfloat16* h2   = (__hip_bfloat16*)carve((size_t)B_SZ * H_SZ * 2);
  __hip_bfloat16* WdT2 = (__hip_bfloat16*)carve((size_t)2 * 96 * 1024 * 2);

  hipMemsetAsync(h0, 0, (size_t)B_SZ * H_SZ * 2, stream);
  hipMemsetAsync(cbuf, 0, (size_t)B_SZ * H_SZ * 4, stream);

  pack_w<<<dim3(64, 18), 256, 0, stream>>>(Wk, Wr, WT2);
  pack_x<<<dim3(32, B_SZ), 256, 0, stream>>>(x, xp);
  pack_wd<<<96, 256, 0, stream>>>(Wd, WdT2);

  __hip_bfloat16* hbuf[2] = {h0, h1b};
  for (int t = 0; t < T_SZ; ++t) {
    const __hip_bfloat16* xpt = xp + (size_t)t * B_SZ * KX;
    lstm_step<<<256, 512, 0, stream>>>(xpt, hbuf[t & 1], hbuf[(t + 1) & 1], cbuf, WT2, b,
                                       (t == T_SZ - 1) ? h2 : nullptr);
  }

  // final h is in hbuf[T&1] = hbuf[0]
  dense_k<<<32, 256, 0, stream>>>(hbuf[0], h2, WdT2, bd, out);
}

// Round 3
// 2989.095 us; speedup vs baseline: 1.4673x; 1.0369x over previous
//
#include <hip/hip_runtime.h>
#include <hip/hip_bf16.h>

#define B_SZ 4096
#define T_SZ 64
#define F_SZ 89
#define H_SZ 1024
#define O_SZ 89
#define KX   128
#define KTOT (KX + H_SZ)   // 1152
#define NSL  (KTOT / 32)   // 36 K-slices of 32

typedef __attribute__((ext_vector_type(8))) short bf16x8;
typedef __attribute__((ext_vector_type(4))) float f32x4;

__device__ __forceinline__ void gload_lds16(const void* g, void* l) {
  __builtin_amdgcn_global_load_lds((const __attribute__((address_space(1))) void*)g,
                                   (__attribute__((address_space(3))) void*)l,
                                   16, 0, 0);
}
__device__ __forceinline__ float sigmoidf_(float x) {
  return 1.0f / (1.0f + __expf(-x));
}

// WT2 packed: n' = (h>>4)*64 + g*16 + (h&15), bf16, [4096][1152] k-contiguous rows.
__global__ __launch_bounds__(256) void pack_w(const float* __restrict__ Wk,
                                              const float* __restrict__ Wr,
                                              __hip_bfloat16* __restrict__ WT2) {
  __shared__ float tile[64][65];
  const int n0 = blockIdx.x * 64;
  const int k0 = blockIdx.y * 64;
  const int c  = threadIdx.x & 63;
  const int rq = threadIdx.x >> 6;
  for (int j = 0; j < 16; ++j) {
    int kk = rq * 16 + j;
    int k = k0 + kk;
    float v;
    if (k < KX) v = (k < F_SZ) ? Wk[(size_t)k * 4096 + n0 + c] : 0.0f;
    else        v = Wr[(size_t)(k - KX) * 4096 + n0 + c];
    tile[kk][c] = v;
  }
  __syncthreads();
  for (int j = 0; j < 16; ++j) {
    int R = n0 + rq * 16 + j;          // orig row: g*1024 + h
    int g = R >> 10, h = R & 1023;
    int np = ((h >> 4) << 6) + (g << 4) + (h & 15);
    WT2[(size_t)np * KTOT + k0 + c] = __float2bfloat16(tile[c][rq * 16 + j]);
  }
}

// xp [T][B][128] bf16, zero-padded cols 89..127. Wave-per-row, fully coalesced.
__global__ __launch_bounds__(256) void pack_x(const float* __restrict__ x,
                                              __hip_bfloat16* __restrict__ xp) {
  const int wid = (blockIdx.x * 256 + threadIdx.x) >> 6;  // 0..8191
  const int l   = threadIdx.x & 63;
  for (int r = wid; r < T_SZ * B_SZ; r += 8192) {
    const int t = r >> 12, m = r & 4095;
    const float* src = x + ((size_t)m * T_SZ + t) * F_SZ;
    float v0 = src[l];
    float v1 = (64 + l < F_SZ) ? src[64 + l] : 0.0f;
    __hip_bfloat16* dst = xp + (size_t)r * KX;
    dst[l]      = __float2bfloat16(v0);
    dst[64 + l] = __float2bfloat16(v1);
  }
}

// WdT2[2][96][1024] bf16: pass0 = bf16(Wd^T), pass1 = bf16(Wd^T - pass0)
__global__ __launch_bounds__(256) void pack_wd(const float* __restrict__ Wd,
                                               __hip_bfloat16* __restrict__ WdT2) {
  int o = blockIdx.x;  // 0..95
  for (int k = threadIdx.x; k < 1024; k += 256) {
    float v = (o < O_SZ) ? Wd[(size_t)k * O_SZ + o] : 0.0f;
    __hip_bfloat16 w1 = __float2bfloat16(v);
    WdT2[(size_t)o * 1024 + k] = w1;
    WdT2[96 * 1024 + (size_t)o * 1024 + k] = __float2bfloat16(v - __bfloat162float(w1));
  }
}

// ---------------- LSTM step: 256x256 tile, ring-of-4 K-slice-32 pipeline ----------------
// LDS: A slots [4][256 rows][64B] @0 (64KB), B slots @65536 (64KB).
// Slice ks uses slot ks&3; stages slice ks+2 into slot (ks+2)&3 (dead since ks-2).
// Slice-entry wait: counted vmcnt(4) — slice ks+2's 4 loads stay in flight. 1 barrier/slice.
__global__ __launch_bounds__(512, 2)
void lstm_step(const __hip_bfloat16* __restrict__ xp_t,   // [4096][128]
               const __hip_bfloat16* __restrict__ h_in,   // [4096][1024]
               __hip_bfloat16* __restrict__ h_out,
               float* __restrict__ cbuf,
               const __hip_bfloat16* __restrict__ WT2,    // [4096][1152] packed
               const float* __restrict__ bias,
               __hip_bfloat16* __restrict__ h2_out)       // null or bf16 residual of h
{
  __shared__ __attribute__((aligned(1024))) char smem[131072];

  const int tid  = threadIdx.x;
  const int lane = tid & 63;
  const int w    = tid >> 6;
  const int wm   = w >> 2;     // 0..1  (M half)
  const int wn   = w & 3;      // 0..3  (64-packed-col strip)

  // XCD-aware swizzle (256 wgs, 8 XCDs): XCD x owns bx in {2x,2x+1} -> h rows L2-local
  const int bid = blockIdx.x;
  const int wg  = (bid & 7) * 32 + (bid >> 3);
  const int bx  = wg >> 4;
  const int by  = wg & 15;
  const int m0  = bx * 256;

  // staging: per wave, round j in {0,1}: rows [(j*8+w)*16, +16), lane l -> row +(l>>2),
  // chunk (l&3); source chunk inverse-swizzled: (l&3) ^ ((l>>2)&3)   (row&3 == (l>>2)&3)
  const int s_rl   = lane >> 2;                       // 0..15 row within round-group
  const int s_cb   = (((lane & 3) ^ ((lane >> 2) & 3)) << 4);  // src col byte (swizzled)
  // frag read swizzle: chunk = lq ^ (row&3) = lq ^ (lr&3)
  const int lr = lane & 15, lq = lane >> 4;
  const int cc = ((lq ^ (lr & 3)) << 4);

  const char* bsrc0 = (const char*)(WT2 + (size_t)by * 256 * KTOT);

  f32x4 acc[8][4];
#pragma unroll
  for (int mi = 0; mi < 8; ++mi)
#pragma unroll
    for (int ni = 0; ni < 4; ++ni) acc[mi][ni] = (f32x4){0.f, 0.f, 0.f, 0.f};

  auto stageA = [&](int s) {   // slice s -> A slot s&3 (2 gload_lds instr)
    const char* base; int ldb;
    if (s < 4) { base = (const char*)xp_t + ((size_t)m0 * KX) * 2 + s * 64;              ldb = KX * 2; }
    else       { base = (const char*)h_in + ((size_t)m0 * H_SZ) * 2 + (s * 64 - 256);    ldb = H_SZ * 2; }
    char* slot = smem + (s & 3) * 16384;
#pragma unroll
    for (int j = 0; j < 2; ++j) {
      int row = (j * 8 + w) * 16 + s_rl;
      gload_lds16(base + (size_t)row * ldb + s_cb, slot + (j * 8 + w) * 1024);
    }
  };
  auto stageB = [&](int s) {   // slice s -> B slot s&3
    char* slot = smem + 65536 + (s & 3) * 16384;
#pragma unroll
    for (int j = 0; j < 2; ++j) {
      int row = (j * 8 + w) * 16 + s_rl;
      gload_lds16(bsrc0 + (size_t)row * (KTOT * 2) + s * 64 + s_cb, slot + (j * 8 + w) * 1024);
    }
  };

  // prologue: stage slices 0,1 (order A0,B0,A1,B1); counted wait drains slice 0 only
  stageA(0); stageB(0);
  stageA(1); stageB(1);
  asm volatile("s_waitcnt vmcnt(4)" ::: "memory");
  __builtin_amdgcn_s_barrier();

  for (int ks = 0; ks < NSL; ++ks) {
    const char* Aslot = smem + (ks & 3) * 16384;
    const char* Bslot = smem + 65536 + (ks & 3) * 16384;

    bf16x8 Bf[4], Af0[4], Af1[4];
#pragma unroll
    for (int ni = 0; ni < 4; ++ni)
      Bf[ni] = *(const bf16x8*)(Bslot + (wn * 64 + ni * 16 + lr) * 64 + cc);
#pragma unroll
    for (int mi = 0; mi < 4; ++mi)
      Af0[mi] = *(const bf16x8*)(Aslot + (wm * 128 + mi * 16 + lr) * 64 + cc);
    if (ks < NSL - 2) stageA(ks + 2);

    __builtin_amdgcn_s_setprio(1);
#pragma unroll
    for (int mi = 0; mi < 4; ++mi)
#pragma unroll
      for (int ni = 0; ni < 4; ++ni)
        acc[mi][ni] = __builtin_amdgcn_mfma_f32_16x16x32_bf16(Af0[mi], Bf[ni], acc[mi][ni], 0, 0, 0);

#pragma unroll
    for (int mi = 0; mi < 4; ++mi)
      Af1[mi] = *(const bf16x8*)(Aslot + (wm * 128 + (mi + 4) * 16 + lr) * 64 + cc);
    if (ks < NSL - 2) stageB(ks + 2);

#pragma unroll
    for (int mi = 0; mi < 4; ++mi)
#pragma unroll
      for (int ni = 0; ni < 4; ++ni)
        acc[mi + 4][ni] = __builtin_amdgcn_mfma_f32_16x16x32_bf16(Af1[mi], Bf[ni], acc[mi + 4][ni], 0, 0, 0);
    __builtin_amdgcn_s_setprio(0);

    // boundary: verify slot for slice ks+1 (its 4 loads are the OLDEST in flight);
    // slice ks+2's 4 loads stay in flight across the barrier (never drain to 0 mid-loop)
    if (ks < NSL - 2)       asm volatile("s_waitcnt vmcnt(4)" ::: "memory");
    else if (ks == NSL - 2) asm volatile("s_waitcnt vmcnt(0)" ::: "memory");
    if (ks < NSL - 1) __builtin_amdgcn_s_barrier();
  }

  // ---- epilogue: all 4 gates wave-local (ni == gate via WT2 packing) ----
  const int hcol = by * 64 + wn * 16 + lr;
  const float b0 = bias[hcol];
  const float b1 = bias[H_SZ + hcol];
  const float b2 = bias[2 * H_SZ + hcol];
  const float b3 = bias[3 * H_SZ + hcol];
#pragma unroll
  for (int mi = 0; mi < 8; ++mi) {
#pragma unroll
    for (int v = 0; v < 4; ++v) {
      int r = m0 + wm * 128 + mi * 16 + lq * 4 + v;
      size_t idx = (size_t)r * H_SZ + hcol;
      float iv = sigmoidf_(acc[mi][0][v] + b0);
      float fv = sigmoidf_(acc[mi][1][v] + b1);
      float gv = fmaxf(acc[mi][2][v] + b2, 0.0f);
      float ov = sigmoidf_(acc[mi][3][v] + b3);
      float cn = fv * cbuf[idx] + iv * gv;
      cbuf[idx] = cn;
      float hv = ov * fmaxf(cn, 0.0f);
      __hip_bfloat16 h1 = __float2bfloat16(hv);
      h_out[idx] = h1;
      if (h2_out) h2_out[idx] = __float2bfloat16(hv - __bfloat162float(h1));
    }
  }
}

// ---------------- dense: out = h @ Wd + bd via 3-pass bf16 MFMA (fp32-accurate) ----------------
// BM=64, 64 blocks, 4 waves x 16 rows each.
__global__ __launch_bounds__(256)
void dense_k(const __hip_bfloat16* __restrict__ h1,
             const __hip_bfloat16* __restrict__ h2,
             const __hip_bfloat16* __restrict__ WdT2,  // [2][96][1024]
             const float* __restrict__ bd,
             float* __restrict__ out) {
  __shared__ __attribute__((aligned(1024))) char smem[8192 + 12288]; // A[64][128B] + B[96][128B]
  const int tid = threadIdx.x, lane = tid & 63, w = tid >> 6;
  const int m0 = blockIdx.x * 64;
  const int lr = lane & 15, lq = lane >> 4;
  const int xb5 = ((lr >> 2) & 1) << 5;

  f32x4 acc[6];
#pragma unroll
  for (int ni = 0; ni < 6; ++ni) acc[ni] = (f32x4){0.f, 0.f, 0.f, 0.f};

  for (int p = 0; p < 3; ++p) {
    const __hip_bfloat16* Asrc = (p < 2) ? h1 : h2;
    const __hip_bfloat16* Bsrc = WdT2 + (p == 1 ? 96 * 1024 : 0);
    for (int kb = 0; kb < 16; ++kb) {
      __syncthreads();  // previous reads done before overwrite
#pragma unroll
      for (int j = 0; j < 2; ++j) {
        int row = j * 32 + (tid >> 3);
        int scol = ((lane & 7) * 16) ^ ((((row) >> 2) & 1) << 5);
        gload_lds16((const char*)(Asrc + (size_t)(m0 + row) * 1024 + kb * 64) + scol,
                    smem + j * 4096 + w * 1024);
      }
#pragma unroll
      for (int j = 0; j < 3; ++j) {
        int row = j * 32 + (tid >> 3);
        int scol = ((lane & 7) * 16) ^ ((((row) >> 2) & 1) << 5);
        gload_lds16((const char*)(Bsrc + (size_t)row * 1024 + kb * 64) + scol,
                    smem + 8192 + j * 4096 + w * 1024);
      }
      __syncthreads();  // hipcc drains vmcnt(0) before barrier -> data resident

      bf16x8 Af[2], Bf[6][2];
#pragma unroll
      for (int ks = 0; ks < 2; ++ks)
        Af[ks] = *(const bf16x8*)(smem + (w * 16 + lr) * 128 + ((ks * 64 + lq * 16) ^ xb5));
#pragma unroll
      for (int ni = 0; ni < 6; ++ni)
#pragma unroll
        for (int ks = 0; ks < 2; ++ks)
          Bf[ni][ks] = *(const bf16x8*)(smem + 8192 + (ni * 16 + lr) * 128 + ((ks * 64 + lq * 16) ^ xb5));
#pragma unroll
      for (int ni = 0; ni < 6; ++ni)
#pragma unroll
        for (int ks = 0; ks < 2; ++ks)
          acc[ni] = __builtin_amdgcn_mfma_f32_16x16x32_bf16(Af[ks], Bf[ni][ks], acc[ni], 0, 0, 0);
    }
  }

#pragma unroll
  for (int ni = 0; ni < 6; ++ni) {
    int o = ni * 16 + lr;
    if (o < O_SZ) {
      float bv = bd[o];
#pragma unroll
      for (int v = 0; v < 4; ++v) {
        int r = m0 + w * 16 + lq * 4 + v;
        out[(size_t)r * O_SZ + o] = acc[ni][v] + bv;
      }
    }
  }
}

extern "C" void kernel_launch(void* const* d_in, const int* in_sizes, int n_in,
                              void* d_out, int out_size, void* d_ws, size_t ws_size,
                              hipStream_t stream) {
  const float* x  = (const float*)d_in[0];
  const float* Wk = (const float*)d_in[1];
  const float* Wr = (const float*)d_in[2];
  const float* b  = (const float*)d_in[3];
  const float* Wd = (const float*)d_in[4];
  const float* bd = (const float*)d_in[5];
  float* out = (float*)d_out;

  char* ws = (char*)d_ws;
  size_t off = 0;
  auto carve = [&](size_t bytes) -> char* {
    char* p = ws + off;
    off += (bytes + 255) & ~(size_t)255;
    return p;
  };
  __hip_bfloat16* WT2  = (__hip_bfloat16*)carve((size_t)4096 * KTOT * 2);
  __hip_bfloat16* xp   = (__hip_bfloat16*)carve((size_t)T_SZ * B_SZ * KX * 2);
  __hip_bfloat16* h0   = (__hip_bfloat16*)carve((size_t)B_SZ * H_SZ * 2);
  __hip_bfloat16* h1b  = (__hip_bfloat16*)carve((size_t)B_SZ * H_SZ * 2);
  float*          cbuf = (float*)carve((size_t)B_SZ * H_SZ * 4);
  __hip_bfloat16* h2   = (__hip_bfloat16*)carve((size_t)B_SZ * H_SZ * 2);
  __hip_bfloat16* WdT2 = (__hip_bfloat16*)carve((size_t)2 * 96 * 1024 * 2);

  hipMemsetAsync(h0, 0, (size_t)B_SZ * H_SZ * 2, stream);
  hipMemsetAsync(cbuf, 0, (size_t)B_SZ * H_SZ * 4, stream);

  pack_w<<<dim3(64, 18), 256, 0, stream>>>(Wk, Wr, WT2);
  pack_x<<<2048, 256, 0, stream>>>(x, xp);
  pack_wd<<<96, 256, 0, stream>>>(Wd, WdT2);

  __hip_bfloat16* hbuf[2] = {h0, h1b};
  for (int t = 0; t < T_SZ; ++t) {
    const __hip_bfloat16* xpt = xp + (size_t)t * B_SZ * KX;
    lstm_step<<<256, 512, 0, stream>>>(xpt, hbuf[t & 1], hbuf[(t + 1) & 1], cbuf, WT2, b,
                                       (t == T_SZ - 1) ? h2 : nullptr);
  }

  // final h is in hbuf[T&1] = hbuf[0]
  dense_k<<<64, 256, 0, stream>>>(hbuf[0], h2, WdT2, bd, out);
}

// Round 4
// 2964.458 us; speedup vs baseline: 1.4795x; 1.0083x over previous
//
#include <hip/hip_runtime.h>
#include <hip/hip_bf16.h>

#define B_SZ 4096
#define T_SZ 64
#define F_SZ 89
#define H_SZ 1024
#define O_SZ 89
#define KX   128
#define KTOT (KX + H_SZ)   // 1152
#define NSL  (KTOT / 32)   // 36 K-slices of 32

typedef __attribute__((ext_vector_type(8))) short bf16x8;
typedef __attribute__((ext_vector_type(4))) float f32x4;

__device__ __forceinline__ void gload_lds16(const void* g, void* l) {
  __builtin_amdgcn_global_load_lds((const __attribute__((address_space(1))) void*)g,
                                   (__attribute__((address_space(3))) void*)l,
                                   16, 0, 0);
}
__device__ __forceinline__ float sigmoidf_(float x) {
  return 1.0f / (1.0f + __expf(-x));
}

// WT2 packed: n' = (h>>4)*64 + g*16 + (h&15), bf16, [4096][1152] k-contiguous rows.
__global__ __launch_bounds__(256) void pack_w(const float* __restrict__ Wk,
                                              const float* __restrict__ Wr,
                                              __hip_bfloat16* __restrict__ WT2) {
  __shared__ float tile[64][65];
  const int n0 = blockIdx.x * 64;
  const int k0 = blockIdx.y * 64;
  const int c  = threadIdx.x & 63;
  const int rq = threadIdx.x >> 6;
  for (int j = 0; j < 16; ++j) {
    int kk = rq * 16 + j;
    int k = k0 + kk;
    float v;
    if (k < KX) v = (k < F_SZ) ? Wk[(size_t)k * 4096 + n0 + c] : 0.0f;
    else        v = Wr[(size_t)(k - KX) * 4096 + n0 + c];
    tile[kk][c] = v;
  }
  __syncthreads();
  for (int j = 0; j < 16; ++j) {
    int R = n0 + rq * 16 + j;          // orig row: g*1024 + h
    int g = R >> 10, h = R & 1023;
    int np = ((h >> 4) << 6) + (g << 4) + (h & 15);
    WT2[(size_t)np * KTOT + k0 + c] = __float2bfloat16(tile[c][rq * 16 + j]);
  }
}

// xp [T][B][128] bf16, zero-padded cols 89..127. Wave-per-row, fully coalesced.
__global__ __launch_bounds__(256) void pack_x(const float* __restrict__ x,
                                              __hip_bfloat16* __restrict__ xp) {
  const int wid = (blockIdx.x * 256 + threadIdx.x) >> 6;  // 0..8191
  const int l   = threadIdx.x & 63;
  for (int r = wid; r < T_SZ * B_SZ; r += 8192) {
    const int t = r >> 12, m = r & 4095;
    const float* src = x + ((size_t)m * T_SZ + t) * F_SZ;
    float v0 = src[l];
    float v1 = (64 + l < F_SZ) ? src[64 + l] : 0.0f;
    __hip_bfloat16* dst = xp + (size_t)r * KX;
    dst[l]      = __float2bfloat16(v0);
    dst[64 + l] = __float2bfloat16(v1);
  }
}

// WdT2[2][96][1024] bf16: pass0 = bf16(Wd^T), pass1 = bf16(Wd^T - pass0)
__global__ __launch_bounds__(256) void pack_wd(const float* __restrict__ Wd,
                                               __hip_bfloat16* __restrict__ WdT2) {
  int o = blockIdx.x;  // 0..95
  for (int k = threadIdx.x; k < 1024; k += 256) {
    float v = (o < O_SZ) ? Wd[(size_t)k * O_SZ + o] : 0.0f;
    __hip_bfloat16 w1 = __float2bfloat16(v);
    WdT2[(size_t)o * 1024 + k] = w1;
    WdT2[96 * 1024 + (size_t)o * 1024 + k] = __float2bfloat16(v - __bfloat162float(w1));
  }
}

// ---------------- LSTM step: 256x256 tile, ring-of-4 K-slice-32 pipeline ----------------
// LDS: A slots [4][256 rows][64B] @0 (64KB), B slots @65536 (64KB).
// Swizzle (both-sides involution, rule 21): LDS (row r, chunk c) holds global chunk
// c ^ ((r>>1)&3) -> every 16-lane lq-group spreads over all 8 bank-quads, 2-way max (free).
// Slice ks: read slot ks&3 (12 ds_read_b128 issued up-front), stage slice ks+2, 32 MFMA,
// boundary vmcnt(4) (slice ks+2's loads stay in flight), 1 barrier/slice.
__global__ __launch_bounds__(512, 2)
void lstm_step(const __hip_bfloat16* __restrict__ xp_t,   // [4096][128]
               const __hip_bfloat16* __restrict__ h_in,   // [4096][1024]
               __hip_bfloat16* __restrict__ h_out,
               float* __restrict__ cbuf,
               const __hip_bfloat16* __restrict__ WT2,    // [4096][1152] packed
               const float* __restrict__ bias,
               __hip_bfloat16* __restrict__ h2_out)       // null or bf16 residual of h
{
  __shared__ __attribute__((aligned(1024))) char smem[131072];

  const int tid  = threadIdx.x;
  const int lane = tid & 63;
  const int w    = tid >> 6;
  const int wm   = w >> 2;     // 0..1  (M half)
  const int wn   = w & 3;      // 0..3  (64-packed-col strip)

  // XCD-aware swizzle (256 wgs, 8 XCDs)
  const int bid = blockIdx.x;
  const int wg  = (bid & 7) * 32 + (bid >> 3);
  const int bx  = wg >> 4;
  const int by  = wg & 15;
  const int m0  = bx * 256;

  // staging: lane l writes LDS (row base+(l>>2), chunk l&3); source chunk = (l&3)^((l>>3)&3)
  const int s_rl = lane >> 2;
  const int s_cb = (((lane & 3) ^ ((lane >> 3) & 3)) << 4);
  // frag read: global chunk lq at row base+lr -> LDS chunk lq ^ ((lr>>1)&3)
  const int lr = lane & 15, lq = lane >> 4;
  const int cc = ((lq ^ ((lr >> 1) & 3)) << 4);

  const char* bsrc0 = (const char*)(WT2 + (size_t)by * 256 * KTOT);

  f32x4 acc[8][4];
#pragma unroll
  for (int mi = 0; mi < 8; ++mi)
#pragma unroll
    for (int ni = 0; ni < 4; ++ni) acc[mi][ni] = (f32x4){0.f, 0.f, 0.f, 0.f};

  auto stageA = [&](int s) {   // slice s -> A slot s&3 (2 gload_lds)
    const char* base; int ldb;
    if (s < 4) { base = (const char*)xp_t + ((size_t)m0 * KX) * 2 + s * 64;           ldb = KX * 2; }
    else       { base = (const char*)h_in + ((size_t)m0 * H_SZ) * 2 + (s * 64 - 256); ldb = H_SZ * 2; }
    char* slot = smem + (s & 3) * 16384;
#pragma unroll
    for (int j = 0; j < 2; ++j) {
      int row = (j * 8 + w) * 16 + s_rl;
      gload_lds16(base + (size_t)row * ldb + s_cb, slot + (j * 8 + w) * 1024);
    }
  };
  auto stageB = [&](int s) {   // slice s -> B slot s&3
    char* slot = smem + 65536 + (s & 3) * 16384;
#pragma unroll
    for (int j = 0; j < 2; ++j) {
      int row = (j * 8 + w) * 16 + s_rl;
      gload_lds16(bsrc0 + (size_t)row * (KTOT * 2) + s * 64 + s_cb, slot + (j * 8 + w) * 1024);
    }
  };

  // prologue: stage slices 0,1; counted wait leaves slice 1 partially in flight? No:
  // vmcnt(4) waits slice 0's 4 loads (oldest), slice 1's 4 stay in flight.
  stageA(0); stageB(0);
  stageA(1); stageB(1);
  asm volatile("s_waitcnt vmcnt(4)" ::: "memory");
  __builtin_amdgcn_s_barrier();

  for (int ks = 0; ks < NSL; ++ks) {
    const char* Aslot = smem + (ks & 3) * 16384;
    const char* Bslot = smem + 65536 + (ks & 3) * 16384;

    // ---- issue ALL 12 frag reads up front; compiler's fine lgkmcnt overlaps tail w/ MFMA
    bf16x8 Bf[4], Af[8];
#pragma unroll
    for (int ni = 0; ni < 4; ++ni)
      Bf[ni] = *(const bf16x8*)(Bslot + (wn * 64 + ni * 16 + lr) * 64 + cc);
#pragma unroll
    for (int mi = 0; mi < 8; ++mi)
      Af[mi] = *(const bf16x8*)(Aslot + (wm * 128 + mi * 16 + lr) * 64 + cc);

    // ---- stage slice ks+2 into its (dead) slot ----
    if (ks < NSL - 2) { stageA(ks + 2); stageB(ks + 2); }

    __builtin_amdgcn_s_setprio(1);
#pragma unroll
    for (int mi = 0; mi < 8; ++mi)
#pragma unroll
      for (int ni = 0; ni < 4; ++ni)
        acc[mi][ni] = __builtin_amdgcn_mfma_f32_16x16x32_bf16(Af[mi], Bf[ni], acc[mi][ni], 0, 0, 0);
    __builtin_amdgcn_s_setprio(0);

    // boundary: ensure slice ks+1 resident (its 4 loads are oldest in flight);
    // slice ks+2's 4 loads stay in flight across the barrier (never drain mid-loop)
    if (ks < NSL - 2)       asm volatile("s_waitcnt vmcnt(4)" ::: "memory");
    else if (ks == NSL - 2) asm volatile("s_waitcnt vmcnt(0)" ::: "memory");
    if (ks < NSL - 1) __builtin_amdgcn_s_barrier();
  }

  // ---- epilogue: all 4 gates wave-local (ni == gate via WT2 packing) ----
  const int hcol = by * 64 + wn * 16 + lr;
  const float b0 = bias[hcol];
  const float b1 = bias[H_SZ + hcol];
  const float b2 = bias[2 * H_SZ + hcol];
  const float b3 = bias[3 * H_SZ + hcol];
#pragma unroll
  for (int mi = 0; mi < 8; ++mi) {
#pragma unroll
    for (int v = 0; v < 4; ++v) {
      int r = m0 + wm * 128 + mi * 16 + lq * 4 + v;
      size_t idx = (size_t)r * H_SZ + hcol;
      float iv = sigmoidf_(acc[mi][0][v] + b0);
      float fv = sigmoidf_(acc[mi][1][v] + b1);
      float gv = fmaxf(acc[mi][2][v] + b2, 0.0f);
      float ov = sigmoidf_(acc[mi][3][v] + b3);
      float cn = fv * cbuf[idx] + iv * gv;
      cbuf[idx] = cn;
      float hv = ov * fmaxf(cn, 0.0f);
      __hip_bfloat16 h1 = __float2bfloat16(hv);
      h_out[idx] = h1;
      if (h2_out) h2_out[idx] = __float2bfloat16(hv - __bfloat162float(h1));
    }
  }
}

// ---------------- dense: out = h @ Wd + bd via 3-pass bf16 MFMA (fp32-accurate) ----------------
// BM=64, 64 blocks. LDS rows = 128B (8 chunks); involution: chunk c at row r holds
// global chunk c ^ (r&7) -> 2-way max on both ds_read_b128 and linear gload writes.
__global__ __launch_bounds__(256)
void dense_k(const __hip_bfloat16* __restrict__ h1,
             const __hip_bfloat16* __restrict__ h2,
             const __hip_bfloat16* __restrict__ WdT2,  // [2][96][1024]
             const float* __restrict__ bd,
             float* __restrict__ out) {
  __shared__ __attribute__((aligned(1024))) char smem[8192 + 12288]; // A[64][128B] + B[96][128B]
  const int tid = threadIdx.x, lane = tid & 63, w = tid >> 6;
  const int m0 = blockIdx.x * 64;
  const int lr = lane & 15, lq = lane >> 4;
  // staging: lane l -> row base+(l>>3), chunk l&7; source chunk = (l&7)^((l>>3)&7)
  const int s_cb = (((lane & 7) ^ ((lane >> 3) & 7)) << 4);

  f32x4 acc[6];
#pragma unroll
  for (int ni = 0; ni < 6; ++ni) acc[ni] = (f32x4){0.f, 0.f, 0.f, 0.f};

  for (int p = 0; p < 3; ++p) {
    const __hip_bfloat16* Asrc = (p < 2) ? h1 : h2;
    const __hip_bfloat16* Bsrc = WdT2 + (p == 1 ? 96 * 1024 : 0);
    for (int kb = 0; kb < 16; ++kb) {
      __syncthreads();  // previous reads done before overwrite
#pragma unroll
      for (int j = 0; j < 2; ++j) {
        int row = j * 32 + w * 8 + (lane >> 3);
        gload_lds16((const char*)(Asrc + (size_t)(m0 + row) * 1024 + kb * 64) + s_cb,
                    smem + j * 4096 + w * 1024);
      }
#pragma unroll
      for (int j = 0; j < 3; ++j) {
        int row = j * 32 + w * 8 + (lane >> 3);
        gload_lds16((const char*)(Bsrc + (size_t)row * 1024 + kb * 64) + s_cb,
                    smem + 8192 + j * 4096 + w * 1024);
      }
      __syncthreads();  // hipcc drains vmcnt(0) before barrier -> data resident

      bf16x8 Af[2], Bf[6][2];
#pragma unroll
      for (int ks = 0; ks < 2; ++ks)
        Af[ks] = *(const bf16x8*)(smem + (w * 16 + lr) * 128 + (((4 * ks + lq) ^ (lr & 7)) << 4));
#pragma unroll
      for (int ni = 0; ni < 6; ++ni)
#pragma unroll
        for (int ks = 0; ks < 2; ++ks)
          Bf[ni][ks] = *(const bf16x8*)(smem + 8192 + (ni * 16 + lr) * 128 + (((4 * ks + lq) ^ (lr & 7)) << 4));
#pragma unroll
      for (int ni = 0; ni < 6; ++ni)
#pragma unroll
        for (int ks = 0; ks < 2; ++ks)
          acc[ni] = __builtin_amdgcn_mfma_f32_16x16x32_bf16(Af[ks], Bf[ni][ks], acc[ni], 0, 0, 0);
    }
  }

#pragma unroll
  for (int ni = 0; ni < 6; ++ni) {
    int o = ni * 16 + lr;
    if (o < O_SZ) {
      float bv = bd[o];
#pragma unroll
      for (int v = 0; v < 4; ++v) {
        int r = m0 + w * 16 + lq * 4 + v;
        out[(size_t)r * O_SZ + o] = acc[ni][v] + bv;
      }
    }
  }
}

extern "C" void kernel_launch(void* const* d_in, const int* in_sizes, int n_in,
                              void* d_out, int out_size, void* d_ws, size_t ws_size,
                              hipStream_t stream) {
  const float* x  = (const float*)d_in[0];
  const float* Wk = (const float*)d_in[1];
  const float* Wr = (const float*)d_in[2];
  const float* b  = (const float*)d_in[3];
  const float* Wd = (const float*)d_in[4];
  const float* bd = (const float*)d_in[5];
  float* out = (float*)d_out;

  char* ws = (char*)d_ws;
  size_t off = 0;
  auto carve = [&](size_t bytes) -> char* {
    char* p = ws + off;
    off += (bytes + 255) & ~(size_t)255;
    return p;
  };
  __hip_bfloat16* WT2  = (__hip_bfloat16*)carve((size_t)4096 * KTOT * 2);
  __hip_bfloat16* xp   = (__hip_bfloat16*)carve((size_t)T_SZ * B_SZ * KX * 2);
  __hip_bfloat16* h0   = (__hip_bfloat16*)carve((size_t)B_SZ * H_SZ * 2);
  __hip_bfloat16* h1b  = (__hip_bfloat16*)carve((size_t)B_SZ * H_SZ * 2);
  float*          cbuf = (float*)carve((size_t)B_SZ * H_SZ * 4);
  __hip_bfloat16* h2   = (__hip_bfloat16*)carve((size_t)B_SZ * H_SZ * 2);
  __hip_bfloat16* WdT2 = (__hip_bfloat16*)carve((size_t)2 * 96 * 1024 * 2);

  hipMemsetAsync(h0, 0, (size_t)B_SZ * H_SZ * 2, stream);
  hipMemsetAsync(cbuf, 0, (size_t)B_SZ * H_SZ * 4, stream);

  pack_w<<<dim3(64, 18), 256, 0, stream>>>(Wk, Wr, WT2);
  pack_x<<<2048, 256, 0, stream>>>(x, xp);
  pack_wd<<<96, 256, 0, stream>>>(Wd, WdT2);

  __hip_bfloat16* hbuf[2] = {h0, h1b};
  for (int t = 0; t < T_SZ; ++t) {
    const __hip_bfloat16* xpt = xp + (size_t)t * B_SZ * KX;
    lstm_step<<<256, 512, 0, stream>>>(xpt, hbuf[t & 1], hbuf[(t + 1) & 1], cbuf, WT2, b,
                                       (t == T_SZ - 1) ? h2 : nullptr);
  }

  // final h is in hbuf[T&1] = hbuf[0]
  dense_k<<<64, 256, 0, stream>>>(hbuf[0], h2, WdT2, bd, out);
}